// Round 1
// baseline (458.583 us; speedup 1.0000x reference)
//
#include <hip/hip_runtime.h>
#include <hip/hip_bf16.h>

typedef float f32x4 __attribute__((ext_vector_type(4)));
typedef short s16x8 __attribute__((ext_vector_type(8)));

__device__ __forceinline__ unsigned short f2bf(float x){
  unsigned u = __float_as_uint(x);
  u += 0x7fffu + ((u >> 16) & 1u);
  return (unsigned short)(u >> 16);
}
__device__ __forceinline__ float bf2f(unsigned short h){
  return __uint_as_float(((unsigned)h) << 16);
}

// ---------------- setup: ww[c][h] = ln_z_w[c]*w_z[c][h] (bf16); T/U sums ----------------
__global__ void setup_kernel(const float* __restrict__ lnzw, const float* __restrict__ lnzb,
                             const float* __restrict__ w_z, unsigned short* __restrict__ wwB,
                             float* __restrict__ TU){
  int t = threadIdx.x;
  if (t < 128){
    float lw = lnzw[t];
    #pragma unroll
    for (int h = 0; h < 16; ++h) wwB[t*16 + h] = f2bf(lw * w_z[t*16 + h]);
  }
  if (t < 16){
    float T = 0.f, U = 0.f;
    for (int c = 0; c < 128; ++c){ T += lnzw[c]*w_z[c*16 + t]; U += lnzb[c]*w_z[c*16 + t]; }
    TU[t] = T; TU[16 + t] = U;
  }
}

// ---------------- LN of a: one wave per row ----------------
__global__ void ln_a_kernel(const float* __restrict__ a, const float* __restrict__ w,
                            const float* __restrict__ b, float* __restrict__ a_ln){
  int r = blockIdx.x, l = threadIdx.x;
  const float* ap = a + (size_t)r*384;
  float x[6]; float s = 0.f, sq = 0.f;
  #pragma unroll
  for (int i = 0; i < 6; ++i){ x[i] = ap[i*64 + l]; s += x[i]; sq += x[i]*x[i]; }
  #pragma unroll
  for (int off = 32; off; off >>= 1){ s += __shfl_xor(s, off); sq += __shfl_xor(sq, off); }
  float mu = s*(1.f/384.f);
  float var = sq*(1.f/384.f) - mu*mu;
  float rs = rsqrtf(var + 1e-5f);
  #pragma unroll
  for (int i = 0; i < 6; ++i){ int c = i*64 + l; a_ln[(size_t)r*384 + c] = (x[i]-mu)*rs*w[c] + b[c]; }
}

// ---------------- generic 1024x384 @ 384x384 f32 GEMM, epilogue by mode ----------------
// mode 0: q -> qT[h][n][24] * D^-0.5 ; 1: k -> kT ; 2: v -> vT ;
// mode 3: g = sigmoid(c + bg) -> [n][384] ; mode 4: out = c + bo -> [n][384]
__global__ __launch_bounds__(256) void gemm384(const float* __restrict__ A, const float* __restrict__ B,
                                               const float* __restrict__ bias, float* __restrict__ dst, int mode){
  __shared__ float As[16][68];
  __shared__ float Bs[16][64];
  int tid = threadIdx.x;
  int tx = tid & 15, ty = tid >> 4;
  int n0 = blockIdx.x*64, m0 = blockIdx.y*64;
  float acc[4][4];
  #pragma unroll
  for (int i = 0; i < 4; ++i)
    #pragma unroll
    for (int j = 0; j < 4; ++j) acc[i][j] = 0.f;
  for (int kc = 0; kc < 24; ++kc){
    {
      int m = tid >> 2, k4 = tid & 3;
      float4 v = *(const float4*)(A + (size_t)(m0 + m)*384 + kc*16 + k4*4);
      As[k4*4+0][m] = v.x; As[k4*4+1][m] = v.y; As[k4*4+2][m] = v.z; As[k4*4+3][m] = v.w;
    }
    {
      int kB = tid >> 4, n4 = tid & 15;
      float4 v = *(const float4*)(B + (size_t)(kc*16 + kB)*384 + n0 + n4*4);
      *(float4*)&Bs[kB][n4*4] = v;
    }
    __syncthreads();
    #pragma unroll
    for (int k = 0; k < 16; ++k){
      float4 a4 = *(const float4*)&As[k][ty*4];
      float4 b4 = *(const float4*)&Bs[k][tx*4];
      float av[4] = {a4.x, a4.y, a4.z, a4.w};
      float bv[4] = {b4.x, b4.y, b4.z, b4.w};
      #pragma unroll
      for (int i = 0; i < 4; ++i)
        #pragma unroll
        for (int j = 0; j < 4; ++j) acc[i][j] += av[i]*bv[j];
    }
    __syncthreads();
  }
  #pragma unroll
  for (int i = 0; i < 4; ++i){
    int row = m0 + ty*4 + i;
    #pragma unroll
    for (int j = 0; j < 4; ++j){
      int col = n0 + tx*4 + j;
      float v = acc[i][j];
      if (mode == 0){ int h = col/24, d = col - h*24; dst[((size_t)(h<<10) + row)*24 + d] = v*0.20412414523193154f; }
      else if (mode <= 2){ int h = col/24, d = col - h*24; dst[((size_t)(h<<10) + row)*24 + d] = v; }
      else if (mode == 3){ float t = v + bias[col]; dst[(size_t)row*384 + col] = 1.f/(1.f + __expf(-t)); }
      else { dst[(size_t)row*384 + col] = v + bias[col]; }
    }
  }
}

// ---------------- z bias: LN(z) @ w_z via bf16 MFMA; pb[h][q][k] bf16 ----------------
__global__ __launch_bounds__(256) void zbias_kernel(const float* __restrict__ z, const unsigned short* __restrict__ wwB,
                                                    const float* __restrict__ TU, unsigned short* __restrict__ pb){
  __shared__ short zt[64*16*8];        // 64 pairs x 128 ch bf16, 16B-unit XOR swizzle
  __shared__ float2 stats[64];         // (mu, rs) per pair
  int tid = threadIdx.x;
  int wave = tid >> 6, lane = tid & 63;
  int h = lane & 15, sub = lane >> 4;
  s16x8 bfr[4];
  #pragma unroll
  for (int kc = 0; kc < 4; ++kc)
    #pragma unroll
    for (int j = 0; j < 8; ++j) bfr[kc][j] = (short)wwB[(kc*32 + sub*8 + j)*16 + h];
  float Th = TU[h], Uh = TU[16 + h];
  for (int it = 0; it < 4; ++it){
    int tile = blockIdx.x + it*4096;   // 16384 tiles of 64 pairs
    size_t pairBase = (size_t)tile*64;
    const float4* zin = ((const float4*)z) + pairBase*32;
    #pragma unroll
    for (int i = 0; i < 8; ++i){
      int f4i = i*256 + tid;
      float4 v = zin[f4i];
      int pair = f4i >> 5, c4 = f4i & 31;
      float s = v.x + v.y + v.z + v.w;
      float sq = v.x*v.x + v.y*v.y + v.z*v.z + v.w*v.w;
      #pragma unroll
      for (int off = 16; off; off >>= 1){ s += __shfl_xor(s, off, 32); sq += __shfl_xor(sq, off, 32); }
      if ((lane & 31) == 0){
        float mu = s*(1.f/128.f);
        float var = sq*(1.f/128.f) - mu*mu;
        stats[pair] = make_float2(mu, rsqrtf(var + 1e-5f));
      }
      unsigned lo = ((unsigned)f2bf(v.y) << 16) | (unsigned)f2bf(v.x);
      unsigned hi = ((unsigned)f2bf(v.w) << 16) | (unsigned)f2bf(v.z);
      int u16i = (c4 >> 1) ^ (pair & 7);
      ((uint2*)zt)[(pair*16 + u16i)*2 + (c4 & 1)] = make_uint2(lo, hi);
    }
    __syncthreads();
    int row = wave*16 + (lane & 15);
    f32x4 acc = {0.f, 0.f, 0.f, 0.f};
    const s16x8* zt8 = (const s16x8*)zt;
    #pragma unroll
    for (int kc = 0; kc < 4; ++kc){
      int u = (kc*4 + sub) ^ (row & 7);
      s16x8 af = zt8[row*16 + u];
      acc = __builtin_amdgcn_mfma_f32_16x16x32_bf16(af, bfr[kc], acc, 0, 0, 0);
    }
    #pragma unroll
    for (int r = 0; r < 4; ++r){
      int pl = wave*16 + sub*4 + r;
      float2 st = stats[pl];
      float bias = st.y*(acc[r] - st.x*Th) + Uh;
      pb[((size_t)h << 20) + pairBase + pl] = f2bf(bias);
    }
    __syncthreads();
  }
}

// ---------------- attention: lane = q row, wave = kk chunk; online softmax ----------------
__global__ __launch_bounds__(256) void attn_kernel(const float* __restrict__ qT, const float* __restrict__ kT,
                                                   const float* __restrict__ vT, const unsigned short* __restrict__ pb,
                                                   const float* __restrict__ mask, float* __restrict__ part){
  __shared__ float mlds[4][64][29];
  int s = blockIdx.x, qb = blockIdx.y, h = blockIdx.z;
  int wave = threadIdx.x >> 6, lane = threadIdx.x & 63;
  int q = qb*64 + lane;
  const float4* qp = (const float4*)(qT + ((size_t)(h << 10) + q)*24);
  float qv[24];
  #pragma unroll
  for (int i = 0; i < 6; ++i){ float4 t = qp[i]; qv[4*i] = t.x; qv[4*i+1] = t.y; qv[4*i+2] = t.z; qv[4*i+3] = t.w; }
  const unsigned short* pbrow = pb + ((size_t)h << 20) + (size_t)q*1024;
  float m = -1e30f, lsum = 0.f, ov[24];
  #pragma unroll
  for (int i = 0; i < 24; ++i) ov[i] = 0.f;
  int kk0 = s*256 + wave*64;
  for (int kk = kk0; kk < kk0 + 64; ++kk){
    const float4* kp = (const float4*)(kT + ((size_t)(h << 10) + kk)*24);
    float dot = 0.f;
    #pragma unroll
    for (int i = 0; i < 6; ++i){ float4 kf = kp[i]; dot += qv[4*i]*kf.x + qv[4*i+1]*kf.y + qv[4*i+2]*kf.z + qv[4*i+3]*kf.w; }
    float lg = dot + bf2f(pbrow[kk]) + 1e9f*(mask[kk] - 1.f);
    float mn = fmaxf(m, lg);
    float corr = __expf(m - mn);
    float p = __expf(lg - mn);
    lsum = lsum*corr + p;
    const float4* vp = (const float4*)(vT + ((size_t)(h << 10) + kk)*24);
    #pragma unroll
    for (int i = 0; i < 6; ++i){
      float4 vf = vp[i];
      ov[4*i]   = ov[4*i]  *corr + p*vf.x;
      ov[4*i+1] = ov[4*i+1]*corr + p*vf.y;
      ov[4*i+2] = ov[4*i+2]*corr + p*vf.z;
      ov[4*i+3] = ov[4*i+3]*corr + p*vf.w;
    }
    m = mn;
  }
  mlds[wave][lane][0] = m; mlds[wave][lane][1] = lsum;
  #pragma unroll
  for (int i = 0; i < 24; ++i) mlds[wave][lane][2+i] = ov[i];
  __syncthreads();
  if (wave == 0){
    float M = -1e30f, L = 0.f, O[24];
    #pragma unroll
    for (int i = 0; i < 24; ++i) O[i] = 0.f;
    #pragma unroll
    for (int w = 0; w < 4; ++w){
      float mi = mlds[w][lane][0], li = mlds[w][lane][1];
      float nm = fmaxf(M, mi);
      float c1 = __expf(M - nm), c2 = __expf(mi - nm);
      L = L*c1 + li*c2;
      #pragma unroll
      for (int i = 0; i < 24; ++i) O[i] = O[i]*c1 + mlds[w][lane][2+i]*c2;
      M = nm;
    }
    float* pw = part + ((size_t)((h*16 + qb)*4 + s)*64 + lane)*32;
    pw[0] = M; pw[1] = L;
    #pragma unroll
    for (int i = 0; i < 24; ++i) pw[4+i] = O[i];
  }
}

// ---------------- merge 4 split-partials, apply gate ----------------
__global__ __launch_bounds__(256) void merge_kernel(const float* __restrict__ part, const float* __restrict__ g,
                                                    float* __restrict__ og){
  int gid = blockIdx.x*256 + threadIdx.x;
  int h = gid >> 10, q = gid & 1023;
  float M = -1e30f, L = 0.f, O[24];
  #pragma unroll
  for (int i = 0; i < 24; ++i) O[i] = 0.f;
  #pragma unroll
  for (int sp = 0; sp < 4; ++sp){
    const float* pr = part + ((size_t)((h*16 + (q >> 6))*4 + sp)*64 + (q & 63))*32;
    float mi = pr[0], li = pr[1];
    float nm = fmaxf(M, mi);
    float c1 = __expf(M - nm), c2 = __expf(mi - nm);
    L = L*c1 + li*c2;
    #pragma unroll
    for (int i = 0; i < 24; ++i) O[i] = O[i]*c1 + pr[4+i]*c2;
    M = nm;
  }
  float inv = 1.f/L;
  size_t base = (size_t)q*384 + h*24;
  #pragma unroll
  for (int i = 0; i < 24; ++i) og[base + i] = g[base + i]*O[i]*inv;
}

extern "C" void kernel_launch(void* const* d_in, const int* in_sizes, int n_in,
                              void* d_out, int out_size, void* d_ws, size_t ws_size,
                              hipStream_t stream){
  const float* a      = (const float*)d_in[0];
  const float* z      = (const float*)d_in[1];
  const float* mask   = (const float*)d_in[2];
  const float* ln_a_w = (const float*)d_in[3];
  const float* ln_a_b = (const float*)d_in[4];
  const float* ln_z_w = (const float*)d_in[5];
  const float* ln_z_b = (const float*)d_in[6];
  const float* w_z    = (const float*)d_in[7];
  const float* wq     = (const float*)d_in[8];
  const float* wk     = (const float*)d_in[9];
  const float* wv     = (const float*)d_in[10];
  const float* wg     = (const float*)d_in[11];
  const float* bg     = (const float*)d_in[12];
  const float* wo     = (const float*)d_in[13];
  const float* bo     = (const float*)d_in[14];

  char* ws = (char*)d_ws;
  float* a_ln = (float*)(ws + ((size_t)0u));
  float* qT   = (float*)(ws + ((size_t)2u << 20));
  float* kT   = (float*)(ws + ((size_t)4u << 20));
  float* vT   = (float*)(ws + ((size_t)6u << 20));
  float* g    = (float*)(ws + ((size_t)8u << 20));
  float* og   = (float*)(ws + ((size_t)10u << 20));
  unsigned short* wwB = (unsigned short*)(ws + ((size_t)12u << 20));
  float* TU   = (float*)(ws + ((size_t)12u << 20) + 8192);
  float* part = (float*)(ws + ((size_t)13u << 20));
  unsigned short* pb  = (unsigned short*)(ws + ((size_t)22u << 20));

  hipLaunchKernelGGL(setup_kernel, dim3(1), dim3(256), 0, stream, ln_z_w, ln_z_b, w_z, wwB, TU);
  hipLaunchKernelGGL(ln_a_kernel, dim3(1024), dim3(64), 0, stream, a, ln_a_w, ln_a_b, a_ln);
  hipLaunchKernelGGL(gemm384, dim3(6,16), dim3(256), 0, stream, a_ln, wq, (const float*)nullptr, qT, 0);
  hipLaunchKernelGGL(gemm384, dim3(6,16), dim3(256), 0, stream, a_ln, wk, (const float*)nullptr, kT, 1);
  hipLaunchKernelGGL(gemm384, dim3(6,16), dim3(256), 0, stream, a_ln, wv, (const float*)nullptr, vT, 2);
  hipLaunchKernelGGL(gemm384, dim3(6,16), dim3(256), 0, stream, a_ln, wg, bg, g, 3);
  hipLaunchKernelGGL(zbias_kernel, dim3(4096), dim3(256), 0, stream, z, wwB, TU, pb);
  hipLaunchKernelGGL(attn_kernel, dim3(4,16,16), dim3(256), 0, stream, qT, kT, vT, pb, mask, part);
  hipLaunchKernelGGL(merge_kernel, dim3(64), dim3(256), 0, stream, part, g, og);
  hipLaunchKernelGGL(gemm384, dim3(6,16), dim3(256), 0, stream, og, wo, bo, (float*)d_out, 4);
}

// Round 2
// 340.437 us; speedup vs baseline: 1.3470x; 1.3470x over previous
//
#include <hip/hip_runtime.h>
#include <hip/hip_bf16.h>

typedef float f32x4 __attribute__((ext_vector_type(4)));
typedef short s16x8 __attribute__((ext_vector_type(8)));

__device__ __forceinline__ unsigned short f2bf(float x){
  unsigned u = __float_as_uint(x);
  u += 0x7fffu + ((u >> 16) & 1u);
  return (unsigned short)(u >> 16);
}
__device__ __forceinline__ float bf2f(unsigned short h){
  return __uint_as_float(((unsigned)h) << 16);
}

// ---------------- setup: ww[c][h] = ln_z_w[c]*w_z[c][h] (bf16); T/U sums ----------------
__global__ void setup_kernel(const float* __restrict__ lnzw, const float* __restrict__ lnzb,
                             const float* __restrict__ w_z, unsigned short* __restrict__ wwB,
                             float* __restrict__ TU){
  int t = threadIdx.x;
  if (t < 128){
    float lw = lnzw[t];
    #pragma unroll
    for (int h = 0; h < 16; ++h) wwB[t*16 + h] = f2bf(lw * w_z[t*16 + h]);
  }
  if (t < 16){
    float T = 0.f, U = 0.f;
    for (int c = 0; c < 128; ++c){ T += lnzw[c]*w_z[c*16 + t]; U += lnzb[c]*w_z[c*16 + t]; }
    TU[t] = T; TU[16 + t] = U;
  }
}

// ---------------- wprep: wBt[col][k] bf16, col 0..1535 = concat(q,k,v,g); q scaled ----------------
__global__ void wprep_kernel(const float* __restrict__ wq, const float* __restrict__ wk,
                             const float* __restrict__ wv, const float* __restrict__ wg,
                             unsigned short* __restrict__ wBt){
  int idx = blockIdx.x*256 + threadIdx.x;   // 1536*384 = 589824
  int col = idx / 384, k = idx - col*384;
  int m = col / 384 == 0 ? 0 : 0;           // (placeholder, col<1536)
  int mat = col >> 7;                        // col/128; mat/3 gives matrix since 384=3*128
  int which = mat / 3;                       // 0..3
  int c = col - which*384;
  const float* src = which == 0 ? wq : which == 1 ? wk : which == 2 ? wv : wg;
  float v = src[(size_t)k*384 + c];
  if (which == 0) v *= 0.20412414523193154f; // D^-0.5 folded into q weights
  wBt[idx] = f2bf(v);
  (void)m;
}

// ---------------- LN of a -> bf16: 4 rows per block ----------------
__global__ __launch_bounds__(256) void ln_a_kernel(const float* __restrict__ a, const float* __restrict__ w,
                            const float* __restrict__ b, unsigned short* __restrict__ a_lnB){
  int r = blockIdx.x*4 + (threadIdx.x >> 6), l = threadIdx.x & 63;
  const float* ap = a + (size_t)r*384;
  float x[6]; float s = 0.f, sq = 0.f;
  #pragma unroll
  for (int i = 0; i < 6; ++i){ x[i] = ap[i*64 + l]; s += x[i]; sq += x[i]*x[i]; }
  #pragma unroll
  for (int off = 32; off; off >>= 1){ s += __shfl_xor(s, off); sq += __shfl_xor(sq, off); }
  float mu = s*(1.f/384.f);
  float var = sq*(1.f/384.f) - mu*mu;
  float rs = rsqrtf(var + 1e-5f);
  #pragma unroll
  for (int i = 0; i < 6; ++i){ int c = i*64 + l; a_lnB[(size_t)r*384 + c] = f2bf((x[i]-mu)*rs*w[c] + b[c]); }
}

// ---------------- fused QKVG: [1024x384]bf16 @ [384x1536]bf16 via MFMA ----------------
// block = 64 rows x 64 cols, 4 waves (wave = 16 rows x 64 cols); grid (24,16)
__global__ __launch_bounds__(256) void qkvg_kernel(const unsigned short* __restrict__ AB,
                                                   const unsigned short* __restrict__ wBt,
                                                   const float* __restrict__ bg,
                                                   float* __restrict__ qT, float* __restrict__ kT,
                                                   float* __restrict__ vT, float* __restrict__ g){
  __shared__ short Al[64*8*8];   // [64 rows][8 units of 8 bf16], unit XOR-swizzled by row&7
  __shared__ short Bl[64*8*8];
  int tid = threadIdx.x;
  int wave = tid >> 6, lane = tid & 63, l15 = lane & 15, sub = lane >> 4;
  int n0 = blockIdx.x*64, m0 = blockIdx.y*64;
  f32x4 acc[4];
  #pragma unroll
  for (int c = 0; c < 4; ++c) acc[c] = (f32x4){0.f,0.f,0.f,0.f};
  const s16x8* Ag = (const s16x8*)AB;    // row stride 48 units
  const s16x8* Bg = (const s16x8*)wBt;   // row stride 48 units
  s16x8* Al8 = (s16x8*)Al; s16x8* Bl8 = (s16x8*)Bl;
  for (int ks = 0; ks < 6; ++ks){
    int k0u = ks*8;
    #pragma unroll
    for (int j = 0; j < 2; ++j){
      int idx = tid*2 + j;               // 0..511
      int row = idx >> 3, u = idx & 7;
      Al8[row*8 + (u ^ (row & 7))] = Ag[(size_t)(m0 + row)*48 + k0u + u];
      Bl8[row*8 + (u ^ (row & 7))] = Bg[(size_t)(n0 + row)*48 + k0u + u];
    }
    __syncthreads();
    #pragma unroll
    for (int kk = 0; kk < 2; ++kk){
      int arow = wave*16 + l15;
      s16x8 af = Al8[arow*8 + ((kk*4 + sub) ^ (arow & 7))];
      #pragma unroll
      for (int c = 0; c < 4; ++c){
        int brow = c*16 + l15;
        s16x8 bf = Bl8[brow*8 + ((kk*4 + sub) ^ (brow & 7))];
        acc[c] = __builtin_amdgcn_mfma_f32_16x16x32_bf16(af, bf, acc[c], 0, 0, 0);
      }
    }
    __syncthreads();
  }
  int which = blockIdx.x / 6;            // 0:q 1:k 2:v 3:g
  int cb = n0 - which*384;               // col base within the 384-wide matrix
  #pragma unroll
  for (int c = 0; c < 4; ++c){
    int col = cb + c*16 + l15;
    #pragma unroll
    for (int r = 0; r < 4; ++r){
      int row = m0 + wave*16 + sub*4 + r;
      float v = acc[c][r];
      if (which == 3){
        float t = v + bg[col];
        g[(size_t)row*384 + col] = 1.f/(1.f + __expf(-t));
      } else {
        int h = col/24, d = col - h*24;
        float* dst = which == 0 ? qT : which == 1 ? kT : vT;
        dst[((size_t)(h << 10) + row)*24 + d] = v;
      }
    }
  }
}

// ---------------- z bias: LN(z) @ w_z via bf16 MFMA; pb[h][q][k] bf16 ----------------
__global__ __launch_bounds__(256) void zbias_kernel(const float* __restrict__ z, const unsigned short* __restrict__ wwB,
                                                    const float* __restrict__ TU, unsigned short* __restrict__ pb){
  __shared__ short zt[64*16*8];        // 64 pairs x 128 ch bf16, 16B-unit XOR swizzle
  __shared__ float2 stats[64];         // (mu, rs) per pair
  int tid = threadIdx.x;
  int wave = tid >> 6, lane = tid & 63;
  int h = lane & 15, sub = lane >> 4;
  s16x8 bfr[4];
  #pragma unroll
  for (int kc = 0; kc < 4; ++kc)
    #pragma unroll
    for (int j = 0; j < 8; ++j) bfr[kc][j] = (short)wwB[(kc*32 + sub*8 + j)*16 + h];
  float Th = TU[h], Uh = TU[16 + h];
  for (int it = 0; it < 4; ++it){
    int tile = blockIdx.x + it*4096;   // 16384 tiles of 64 pairs
    size_t pairBase = (size_t)tile*64;
    const f32x4* zin = ((const f32x4*)z) + pairBase*32;
    #pragma unroll
    for (int i = 0; i < 8; ++i){
      int f4i = i*256 + tid;
      f32x4 v = __builtin_nontemporal_load(&zin[f4i]);
      int pair = f4i >> 5, c4 = f4i & 31;
      float s = v.x + v.y + v.z + v.w;
      float sq = v.x*v.x + v.y*v.y + v.z*v.z + v.w*v.w;
      #pragma unroll
      for (int off = 16; off; off >>= 1){ s += __shfl_xor(s, off, 32); sq += __shfl_xor(sq, off, 32); }
      if ((lane & 31) == 0){
        float mu = s*(1.f/128.f);
        float var = sq*(1.f/128.f) - mu*mu;
        stats[pair] = make_float2(mu, rsqrtf(var + 1e-5f));
      }
      unsigned lo = ((unsigned)f2bf(v.y) << 16) | (unsigned)f2bf(v.x);
      unsigned hi = ((unsigned)f2bf(v.w) << 16) | (unsigned)f2bf(v.z);
      int u16i = (c4 >> 1) ^ (pair & 7);
      ((uint2*)zt)[(pair*16 + u16i)*2 + (c4 & 1)] = make_uint2(lo, hi);
    }
    __syncthreads();
    int row = wave*16 + (lane & 15);
    f32x4 acc = {0.f, 0.f, 0.f, 0.f};
    const s16x8* zt8 = (const s16x8*)zt;
    #pragma unroll
    for (int kc = 0; kc < 4; ++kc){
      int u = (kc*4 + sub) ^ (row & 7);
      s16x8 af = zt8[row*16 + u];
      acc = __builtin_amdgcn_mfma_f32_16x16x32_bf16(af, bfr[kc], acc, 0, 0, 0);
    }
    #pragma unroll
    for (int r = 0; r < 4; ++r){
      int pl = wave*16 + sub*4 + r;
      float2 st = stats[pl];
      float bias = st.y*(acc[r] - st.x*Th) + Uh;
      pb[((size_t)h << 20) + pairBase + pl] = f2bf(bias);
    }
    __syncthreads();
  }
}

// ---------------- attention: lane = q row, wave = kk chunk; online softmax ----------------
__global__ __launch_bounds__(256) void attn_kernel(const float* __restrict__ qT, const float* __restrict__ kT,
                                                   const float* __restrict__ vT, const unsigned short* __restrict__ pb,
                                                   const float* __restrict__ mask, float* __restrict__ part){
  __shared__ float mlds[4][64][29];
  int s = blockIdx.x, qb = blockIdx.y, h = blockIdx.z;
  int wave = threadIdx.x >> 6, lane = threadIdx.x & 63;
  int q = qb*64 + lane;
  const float4* qp = (const float4*)(qT + ((size_t)(h << 10) + q)*24);
  float qv[24];
  #pragma unroll
  for (int i = 0; i < 6; ++i){ float4 t = qp[i]; qv[4*i] = t.x; qv[4*i+1] = t.y; qv[4*i+2] = t.z; qv[4*i+3] = t.w; }
  const unsigned short* pbrow = pb + ((size_t)h << 20) + (size_t)q*1024;
  float m = -1e30f, lsum = 0.f, ov[24];
  #pragma unroll
  for (int i = 0; i < 24; ++i) ov[i] = 0.f;
  int kk0 = s*256 + wave*64;
  for (int kk = kk0; kk < kk0 + 64; ++kk){
    const float4* kp = (const float4*)(kT + ((size_t)(h << 10) + kk)*24);
    float dot = 0.f;
    #pragma unroll
    for (int i = 0; i < 6; ++i){ float4 kf = kp[i]; dot += qv[4*i]*kf.x + qv[4*i+1]*kf.y + qv[4*i+2]*kf.z + qv[4*i+3]*kf.w; }
    float lg = dot + bf2f(pbrow[kk]) + 1e9f*(mask[kk] - 1.f);
    float mn = fmaxf(m, lg);
    float corr = __expf(m - mn);
    float p = __expf(lg - mn);
    lsum = lsum*corr + p;
    const float4* vp = (const float4*)(vT + ((size_t)(h << 10) + kk)*24);
    #pragma unroll
    for (int i = 0; i < 6; ++i){
      float4 vf = vp[i];
      ov[4*i]   = ov[4*i]  *corr + p*vf.x;
      ov[4*i+1] = ov[4*i+1]*corr + p*vf.y;
      ov[4*i+2] = ov[4*i+2]*corr + p*vf.z;
      ov[4*i+3] = ov[4*i+3]*corr + p*vf.w;
    }
    m = mn;
  }
  mlds[wave][lane][0] = m; mlds[wave][lane][1] = lsum;
  #pragma unroll
  for (int i = 0; i < 24; ++i) mlds[wave][lane][2+i] = ov[i];
  __syncthreads();
  if (wave == 0){
    float M = -1e30f, L = 0.f, O[24];
    #pragma unroll
    for (int i = 0; i < 24; ++i) O[i] = 0.f;
    #pragma unroll
    for (int w = 0; w < 4; ++w){
      float mi = mlds[w][lane][0], li = mlds[w][lane][1];
      float nm = fmaxf(M, mi);
      float c1 = __expf(M - nm), c2 = __expf(mi - nm);
      L = L*c1 + li*c2;
      #pragma unroll
      for (int i = 0; i < 24; ++i) O[i] = O[i]*c1 + mlds[w][lane][2+i]*c2;
      M = nm;
    }
    float* pw = part + ((size_t)((h*16 + qb)*4 + s)*64 + lane)*32;
    pw[0] = M; pw[1] = L;
    #pragma unroll
    for (int i = 0; i < 24; ++i) pw[4+i] = O[i];
  }
}

// ---------------- merge 4 split-partials, apply gate ----------------
__global__ __launch_bounds__(256) void merge_kernel(const float* __restrict__ part, const float* __restrict__ g,
                                                    float* __restrict__ og){
  int gid = blockIdx.x*256 + threadIdx.x;
  int h = gid >> 10, q = gid & 1023;
  float M = -1e30f, L = 0.f, O[24];
  #pragma unroll
  for (int i = 0; i < 24; ++i) O[i] = 0.f;
  #pragma unroll
  for (int sp = 0; sp < 4; ++sp){
    const float* pr = part + ((size_t)((h*16 + (q >> 6))*4 + sp)*64 + (q & 63))*32;
    float mi = pr[0], li = pr[1];
    float nm = fmaxf(M, mi);
    float c1 = __expf(M - nm), c2 = __expf(mi - nm);
    L = L*c1 + li*c2;
    #pragma unroll
    for (int i = 0; i < 24; ++i) O[i] = O[i]*c1 + pr[4+i]*c2;
    M = nm;
  }
  float inv = 1.f/L;
  size_t base = (size_t)q*384 + h*24;
  #pragma unroll
  for (int i = 0; i < 24; ++i) og[base + i] = g[base + i]*O[i]*inv;
}

// ---------------- f32 GEMM for final projection: og[1024x384] @ wo[384x384] + bo ----------------
__global__ __launch_bounds__(256) void gemm384(const float* __restrict__ A, const float* __restrict__ B,
                                               const float* __restrict__ bias, float* __restrict__ dst){
  __shared__ float As[16][68];
  __shared__ float Bs[16][64];
  int tid = threadIdx.x;
  int tx = tid & 15, ty = tid >> 4;
  int n0 = blockIdx.x*64, m0 = blockIdx.y*64;
  float acc[4][4];
  #pragma unroll
  for (int i = 0; i < 4; ++i)
    #pragma unroll
    for (int j = 0; j < 4; ++j) acc[i][j] = 0.f;
  for (int kc = 0; kc < 24; ++kc){
    {
      int m = tid >> 2, k4 = tid & 3;
      float4 v = *(const float4*)(A + (size_t)(m0 + m)*384 + kc*16 + k4*4);
      As[k4*4+0][m] = v.x; As[k4*4+1][m] = v.y; As[k4*4+2][m] = v.z; As[k4*4+3][m] = v.w;
    }
    {
      int kB = tid >> 4, n4 = tid & 15;
      float4 v = *(const float4*)(B + (size_t)(kc*16 + kB)*384 + n0 + n4*4);
      *(float4*)&Bs[kB][n4*4] = v;
    }
    __syncthreads();
    #pragma unroll
    for (int k = 0; k < 16; ++k){
      float4 a4 = *(const float4*)&As[k][ty*4];
      float4 b4 = *(const float4*)&Bs[k][tx*4];
      float av[4] = {a4.x, a4.y, a4.z, a4.w};
      float bv[4] = {b4.x, b4.y, b4.z, b4.w};
      #pragma unroll
      for (int i = 0; i < 4; ++i)
        #pragma unroll
        for (int j = 0; j < 4; ++j) acc[i][j] += av[i]*bv[j];
    }
    __syncthreads();
  }
  #pragma unroll
  for (int i = 0; i < 4; ++i){
    int row = m0 + ty*4 + i;
    #pragma unroll
    for (int j = 0; j < 4; ++j){
      int col = n0 + tx*4 + j;
      dst[(size_t)row*384 + col] = acc[i][j] + bias[col];
    }
  }
}

extern "C" void kernel_launch(void* const* d_in, const int* in_sizes, int n_in,
                              void* d_out, int out_size, void* d_ws, size_t ws_size,
                              hipStream_t stream){
  const float* a      = (const float*)d_in[0];
  const float* z      = (const float*)d_in[1];
  const float* mask   = (const float*)d_in[2];
  const float* ln_a_w = (const float*)d_in[3];
  const float* ln_a_b = (const float*)d_in[4];
  const float* ln_z_w = (const float*)d_in[5];
  const float* ln_z_b = (const float*)d_in[6];
  const float* w_z    = (const float*)d_in[7];
  const float* wq     = (const float*)d_in[8];
  const float* wk     = (const float*)d_in[9];
  const float* wv     = (const float*)d_in[10];
  const float* wg     = (const float*)d_in[11];
  const float* bg     = (const float*)d_in[12];
  const float* wo     = (const float*)d_in[13];
  const float* bo     = (const float*)d_in[14];

  char* ws = (char*)d_ws;
  unsigned short* a_lnB = (unsigned short*)(ws + ((size_t)0u));
  unsigned short* wBt   = (unsigned short*)(ws + ((size_t)1u << 20));
  float* qT   = (float*)(ws + ((size_t)4u << 20));
  float* kT   = (float*)(ws + ((size_t)6u << 20));
  float* vT   = (float*)(ws + ((size_t)8u << 20));
  float* g    = (float*)(ws + ((size_t)10u << 20));
  float* og   = (float*)(ws + ((size_t)12u << 20));
  unsigned short* wwB = (unsigned short*)(ws + ((size_t)14u << 20));
  float* TU   = (float*)(ws + ((size_t)14u << 20) + 8192);
  float* part = (float*)(ws + ((size_t)15u << 20));
  unsigned short* pb  = (unsigned short*)(ws + ((size_t)24u << 20));

  hipLaunchKernelGGL(setup_kernel, dim3(1), dim3(256), 0, stream, ln_z_w, ln_z_b, w_z, wwB, TU);
  hipLaunchKernelGGL(wprep_kernel, dim3(2304), dim3(256), 0, stream, wq, wk, wv, wg, wBt);
  hipLaunchKernelGGL(ln_a_kernel, dim3(256), dim3(256), 0, stream, a, ln_a_w, ln_a_b, a_lnB);
  hipLaunchKernelGGL(qkvg_kernel, dim3(24,16), dim3(256), 0, stream, a_lnB, wBt, bg, qT, kT, vT, g);
  hipLaunchKernelGGL(zbias_kernel, dim3(4096), dim3(256), 0, stream, z, wwB, TU, pb);
  hipLaunchKernelGGL(attn_kernel, dim3(4,16,16), dim3(256), 0, stream, qT, kT, vT, pb, mask, part);
  hipLaunchKernelGGL(merge_kernel, dim3(64), dim3(256), 0, stream, part, g, og);
  hipLaunchKernelGGL(gemm384, dim3(6,16), dim3(256), 0, stream, og, wo, bo, (float*)d_out);
}

// Round 3
// 301.998 us; speedup vs baseline: 1.5185x; 1.1273x over previous
//
#include <hip/hip_runtime.h>
#include <hip/hip_bf16.h>

typedef float f32x4 __attribute__((ext_vector_type(4)));
typedef short s16x8 __attribute__((ext_vector_type(8)));
typedef short s16x4 __attribute__((ext_vector_type(4)));

__device__ __forceinline__ unsigned short f2bf(float x){
  unsigned u = __float_as_uint(x);
  u += 0x7fffu + ((u >> 16) & 1u);
  return (unsigned short)(u >> 16);
}
__device__ __forceinline__ float bf2f(unsigned short h){
  return __uint_as_float(((unsigned)h) << 16);
}

// ---------------- fused prep: wprep (blocks 0..2303), ln_a (2304..2559), setup (2560) ----------------
__global__ __launch_bounds__(256) void prep_kernel(const float* __restrict__ a, const float* __restrict__ ln_a_w,
                             const float* __restrict__ ln_a_b, const float* __restrict__ lnzw,
                             const float* __restrict__ lnzb, const float* __restrict__ w_z,
                             const float* __restrict__ wq, const float* __restrict__ wk,
                             const float* __restrict__ wv, const float* __restrict__ wg,
                             unsigned short* __restrict__ a_lnB, unsigned short* __restrict__ wBt,
                             unsigned short* __restrict__ wwB, float* __restrict__ TU){
  int bid = blockIdx.x, tid = threadIdx.x;
  if (bid < 2304){
    int idx = bid*256 + tid;                  // 1536*384 = 589824
    int col = idx / 384, k = idx - col*384;
    int which = (col >> 7) / 3;               // 0..3
    int c = col - which*384;
    const float* src = which == 0 ? wq : which == 1 ? wk : which == 2 ? wv : wg;
    float v = src[(size_t)k*384 + c];
    if (which == 0) v *= 0.20412414523193154f;
    wBt[idx] = f2bf(v);
  } else if (bid < 2560){
    int r = (bid - 2304)*4 + (tid >> 6), l = tid & 63;
    const float* ap = a + (size_t)r*384;
    float x[6]; float s = 0.f, sq = 0.f;
    #pragma unroll
    for (int i = 0; i < 6; ++i){ x[i] = ap[i*64 + l]; s += x[i]; sq += x[i]*x[i]; }
    #pragma unroll
    for (int off = 32; off; off >>= 1){ s += __shfl_xor(s, off); sq += __shfl_xor(sq, off); }
    float mu = s*(1.f/384.f);
    float var = sq*(1.f/384.f) - mu*mu;
    float rs = rsqrtf(var + 1e-5f);
    #pragma unroll
    for (int i = 0; i < 6; ++i){ int c = i*64 + l; a_lnB[(size_t)r*384 + c] = f2bf((x[i]-mu)*rs*ln_a_w[c] + ln_a_b[c]); }
  } else {
    if (tid < 128){
      float lw = lnzw[tid];
      #pragma unroll
      for (int h = 0; h < 16; ++h) wwB[tid*16 + h] = f2bf(lw * w_z[tid*16 + h]);
    }
    if (tid < 16){
      float T = 0.f, U = 0.f;
      for (int c = 0; c < 128; ++c){ T += lnzw[c]*w_z[c*16 + tid]; U += lnzb[c]*w_z[c*16 + tid]; }
      TU[tid] = T; TU[16 + tid] = U;
    }
  }
}

// ---------------- fused QKVG: [1024x384]bf16 @ [384x1536]bf16 via MFMA ----------------
__global__ __launch_bounds__(256) void qkvg_kernel(const unsigned short* __restrict__ AB,
                                                   const unsigned short* __restrict__ wBt,
                                                   const float* __restrict__ bg,
                                                   float* __restrict__ qT, float* __restrict__ kT,
                                                   float* __restrict__ vT, float* __restrict__ g){
  __shared__ short Al[64*8*8];   // [64 rows][8 units of 8 bf16], unit XOR-swizzled by row&7
  __shared__ short Bl[64*8*8];
  int tid = threadIdx.x;
  int wave = tid >> 6, lane = tid & 63, l15 = lane & 15, sub = lane >> 4;
  int n0 = blockIdx.x*64, m0 = blockIdx.y*64;
  f32x4 acc[4];
  #pragma unroll
  for (int c = 0; c < 4; ++c) acc[c] = (f32x4){0.f,0.f,0.f,0.f};
  const s16x8* Ag = (const s16x8*)AB;    // row stride 48 units
  const s16x8* Bg = (const s16x8*)wBt;
  s16x8* Al8 = (s16x8*)Al; s16x8* Bl8 = (s16x8*)Bl;
  for (int ks = 0; ks < 6; ++ks){
    int k0u = ks*8;
    #pragma unroll
    for (int j = 0; j < 2; ++j){
      int idx = tid*2 + j;
      int row = idx >> 3, u = idx & 7;
      Al8[row*8 + (u ^ (row & 7))] = Ag[(size_t)(m0 + row)*48 + k0u + u];
      Bl8[row*8 + (u ^ (row & 7))] = Bg[(size_t)(n0 + row)*48 + k0u + u];
    }
    __syncthreads();
    #pragma unroll
    for (int kk = 0; kk < 2; ++kk){
      int arow = wave*16 + l15;
      s16x8 af = Al8[arow*8 + ((kk*4 + sub) ^ (arow & 7))];
      #pragma unroll
      for (int c = 0; c < 4; ++c){
        int brow = c*16 + l15;
        s16x8 bf = Bl8[brow*8 + ((kk*4 + sub) ^ (brow & 7))];
        acc[c] = __builtin_amdgcn_mfma_f32_16x16x32_bf16(af, bf, acc[c], 0, 0, 0);
      }
    }
    __syncthreads();
  }
  int which = blockIdx.x / 6;            // 0:q 1:k 2:v 3:g
  int cb = n0 - which*384;
  #pragma unroll
  for (int c = 0; c < 4; ++c){
    int col = cb + c*16 + l15;
    #pragma unroll
    for (int r = 0; r < 4; ++r){
      int row = m0 + wave*16 + sub*4 + r;
      float v = acc[c][r];
      if (which == 3){
        float t = v + bg[col];
        g[(size_t)row*384 + col] = 1.f/(1.f + __expf(-t));
      } else {
        int h = col/24, d = col - h*24;
        float* dst = which == 0 ? qT : which == 1 ? kT : vT;
        dst[((size_t)(h << 10) + row)*24 + d] = v;
      }
    }
  }
}

// ---------------- z bias: LN(z) @ w_z via bf16 MFMA; pb[h][q][k] bf16, coalesced stores ----------------
__global__ __launch_bounds__(256) void zbias_kernel(const float* __restrict__ z, const unsigned short* __restrict__ wwB,
                                                    const float* __restrict__ TU, unsigned short* __restrict__ pb){
  __shared__ short zt[64*16*8];        // 64 pairs x 128 ch bf16, 16B-unit XOR swizzle
  __shared__ float2 stats[64];         // (mu, rs) per pair
  __shared__ float accT[64][17];       // transposed MFMA result for coalesced pb stores
  int tid = threadIdx.x;
  int wave = tid >> 6, lane = tid & 63;
  int h = lane & 15, sub = lane >> 4;
  s16x8 bfr[4];
  #pragma unroll
  for (int kc = 0; kc < 4; ++kc)
    #pragma unroll
    for (int j = 0; j < 8; ++j) bfr[kc][j] = (short)wwB[(kc*32 + sub*8 + j)*16 + h];
  int eh = tid >> 4, epl0 = (tid & 15)*4;   // epilogue mapping: thread -> (h, pl0..pl0+3)
  float Te = TU[eh], Ue = TU[16 + eh];
  for (int it = 0; it < 4; ++it){
    int tile = blockIdx.x + it*4096;   // 16384 tiles of 64 pairs
    size_t pairBase = (size_t)tile*64;
    const f32x4* zin = ((const f32x4*)z) + pairBase*32;
    #pragma unroll
    for (int i = 0; i < 8; ++i){
      int f4i = i*256 + tid;
      f32x4 v = zin[f4i];
      int pair = f4i >> 5, c4 = f4i & 31;
      float s = v.x + v.y + v.z + v.w;
      float sq = v.x*v.x + v.y*v.y + v.z*v.z + v.w*v.w;
      #pragma unroll
      for (int off = 16; off; off >>= 1){ s += __shfl_xor(s, off, 32); sq += __shfl_xor(sq, off, 32); }
      if ((lane & 31) == 0){
        float mu = s*(1.f/128.f);
        float var = sq*(1.f/128.f) - mu*mu;
        stats[pair] = make_float2(mu, rsqrtf(var + 1e-5f));
      }
      unsigned lo = ((unsigned)f2bf(v.y) << 16) | (unsigned)f2bf(v.x);
      unsigned hi = ((unsigned)f2bf(v.w) << 16) | (unsigned)f2bf(v.z);
      int u16i = (c4 >> 1) ^ (pair & 7);
      ((uint2*)zt)[(pair*16 + u16i)*2 + (c4 & 1)] = make_uint2(lo, hi);
    }
    __syncthreads();
    int row = wave*16 + (lane & 15);
    f32x4 acc = {0.f, 0.f, 0.f, 0.f};
    const s16x8* zt8 = (const s16x8*)zt;
    #pragma unroll
    for (int kc = 0; kc < 4; ++kc){
      int u = (kc*4 + sub) ^ (row & 7);
      s16x8 af = zt8[row*16 + u];
      acc = __builtin_amdgcn_mfma_f32_16x16x32_bf16(af, bfr[kc], acc, 0, 0, 0);
    }
    #pragma unroll
    for (int r = 0; r < 4; ++r) accT[wave*16 + sub*4 + r][h] = acc[r];
    __syncthreads();
    ushort4 ov;
    {
      float2 st0 = stats[epl0+0], st1 = stats[epl0+1], st2 = stats[epl0+2], st3 = stats[epl0+3];
      ov.x = f2bf(st0.y*(accT[epl0+0][eh] - st0.x*Te) + Ue);
      ov.y = f2bf(st1.y*(accT[epl0+1][eh] - st1.x*Te) + Ue);
      ov.z = f2bf(st2.y*(accT[epl0+2][eh] - st2.x*Te) + Ue);
      ov.w = f2bf(st3.y*(accT[epl0+3][eh] - st3.x*Te) + Ue);
    }
    *(ushort4*)(pb + ((size_t)eh << 20) + pairBase + epl0) = ov;
    __syncthreads();
  }
}

// ---------------- attention: lane = q row, wave = kk chunk; grouped online softmax ----------------
__global__ __launch_bounds__(256) void attn_kernel(const float* __restrict__ qT, const float* __restrict__ kT,
                                                   const float* __restrict__ vT, const unsigned short* __restrict__ pb,
                                                   const float* __restrict__ mask, float* __restrict__ part){
  __shared__ float mlds[4][64][29];
  int s = blockIdx.x, qb = blockIdx.y, h = blockIdx.z;
  int wave = threadIdx.x >> 6, lane = threadIdx.x & 63;
  int q = qb*64 + lane;
  const float4* qp = (const float4*)(qT + ((size_t)(h << 10) + q)*24);
  float qv[24];
  #pragma unroll
  for (int i = 0; i < 6; ++i){ float4 t = qp[i]; qv[4*i] = t.x; qv[4*i+1] = t.y; qv[4*i+2] = t.z; qv[4*i+3] = t.w; }
  const unsigned short* pbrow = pb + ((size_t)h << 20) + (size_t)q*1024;
  float m = -1e30f, lsum = 0.f, ov[24];
  #pragma unroll
  for (int i = 0; i < 24; ++i) ov[i] = 0.f;
  int kk0 = s*256 + wave*64;
  for (int grp = 0; grp < 16; ++grp){
    int kkb = kk0 + grp*4;
    s16x4 pbv = *(const s16x4*)(pbrow + kkb);
    float4 mk = *(const float4*)(mask + kkb);
    float lg[4];
    #pragma unroll
    for (int j = 0; j < 4; ++j){
      const float4* kp = (const float4*)(kT + ((size_t)(h << 10) + kkb + j)*24);
      float d0 = 0.f, d1 = 0.f, d2 = 0.f, d3 = 0.f;
      #pragma unroll
      for (int i = 0; i < 6; ++i){
        float4 kf = kp[i];
        d0 += qv[4*i]*kf.x; d1 += qv[4*i+1]*kf.y; d2 += qv[4*i+2]*kf.z; d3 += qv[4*i+3]*kf.w;
      }
      float mb = j == 0 ? mk.x : j == 1 ? mk.y : j == 2 ? mk.z : mk.w;
      lg[j] = (d0 + d1) + (d2 + d3) + bf2f((unsigned short)pbv[j]) + 1e9f*(mb - 1.f);
    }
    float gm = fmaxf(fmaxf(lg[0], lg[1]), fmaxf(lg[2], lg[3]));
    if (gm > m){
      float corr = __expf(m - gm);
      lsum *= corr;
      #pragma unroll
      for (int i = 0; i < 24; ++i) ov[i] *= corr;
      m = gm;
    }
    #pragma unroll
    for (int j = 0; j < 4; ++j){
      float p = __expf(lg[j] - m);
      lsum += p;
      const float4* vp = (const float4*)(vT + ((size_t)(h << 10) + kkb + j)*24);
      #pragma unroll
      for (int i = 0; i < 6; ++i){
        float4 vf = vp[i];
        ov[4*i]   += p*vf.x;
        ov[4*i+1] += p*vf.y;
        ov[4*i+2] += p*vf.z;
        ov[4*i+3] += p*vf.w;
      }
    }
  }
  mlds[wave][lane][0] = m; mlds[wave][lane][1] = lsum;
  #pragma unroll
  for (int i = 0; i < 24; ++i) mlds[wave][lane][2+i] = ov[i];
  __syncthreads();
  if (wave == 0){
    float M = -1e30f, L = 0.f, O[24];
    #pragma unroll
    for (int i = 0; i < 24; ++i) O[i] = 0.f;
    #pragma unroll
    for (int w = 0; w < 4; ++w){
      float mi = mlds[w][lane][0], li = mlds[w][lane][1];
      float nm = fmaxf(M, mi);
      float c1 = __expf(M - nm), c2 = __expf(mi - nm);
      L = L*c1 + li*c2;
      #pragma unroll
      for (int i = 0; i < 24; ++i) O[i] = O[i]*c1 + mlds[w][lane][2+i]*c2;
      M = nm;
    }
    float* pw = part + ((size_t)((h*16 + qb)*4 + s)*64 + lane)*32;
    pw[0] = M; pw[1] = L;
    #pragma unroll
    for (int i = 0; i < 24; ++i) pw[4+i] = O[i];
  }
}

// ---------------- merge 4 split-partials, apply gate ----------------
__global__ __launch_bounds__(256) void merge_kernel(const float* __restrict__ part, const float* __restrict__ g,
                                                    float* __restrict__ og){
  int gid = blockIdx.x*256 + threadIdx.x;
  int h = gid >> 10, q = gid & 1023;
  float M = -1e30f, L = 0.f, O[24];
  #pragma unroll
  for (int i = 0; i < 24; ++i) O[i] = 0.f;
  #pragma unroll
  for (int sp = 0; sp < 4; ++sp){
    const float* pr = part + ((size_t)((h*16 + (q >> 6))*4 + sp)*64 + (q & 63))*32;
    float mi = pr[0], li = pr[1];
    float nm = fmaxf(M, mi);
    float c1 = __expf(M - nm), c2 = __expf(mi - nm);
    L = L*c1 + li*c2;
    #pragma unroll
    for (int i = 0; i < 24; ++i) O[i] = O[i]*c1 + pr[4+i]*c2;
    M = nm;
  }
  float inv = 1.f/L;
  size_t base = (size_t)q*384 + h*24;
  #pragma unroll
  for (int i = 0; i < 24; ++i) og[base + i] = g[base + i]*O[i]*inv;
}

// ---------------- f32 GEMM for final projection: og[1024x384] @ wo[384x384] + bo ----------------
__global__ __launch_bounds__(256) void gemm384(const float* __restrict__ A, const float* __restrict__ B,
                                               const float* __restrict__ bias, float* __restrict__ dst){
  __shared__ float As[16][68];
  __shared__ float Bs[16][64];
  int tid = threadIdx.x;
  int tx = tid & 15, ty = tid >> 4;
  int n0 = blockIdx.x*64, m0 = blockIdx.y*64;
  float acc[4][4];
  #pragma unroll
  for (int i = 0; i < 4; ++i)
    #pragma unroll
    for (int j = 0; j < 4; ++j) acc[i][j] = 0.f;
  for (int kc = 0; kc < 24; ++kc){
    {
      int m = tid >> 2, k4 = tid & 3;
      float4 v = *(const float4*)(A + (size_t)(m0 + m)*384 + kc*16 + k4*4);
      As[k4*4+0][m] = v.x; As[k4*4+1][m] = v.y; As[k4*4+2][m] = v.z; As[k4*4+3][m] = v.w;
    }
    {
      int kB = tid >> 4, n4 = tid & 15;
      float4 v = *(const float4*)(B + (size_t)(kc*16 + kB)*384 + n0 + n4*4);
      *(float4*)&Bs[kB][n4*4] = v;
    }
    __syncthreads();
    #pragma unroll
    for (int k = 0; k < 16; ++k){
      float4 a4 = *(const float4*)&As[k][ty*4];
      float4 b4 = *(const float4*)&Bs[k][tx*4];
      float av[4] = {a4.x, a4.y, a4.z, a4.w};
      float bv[4] = {b4.x, b4.y, b4.z, b4.w};
      #pragma unroll
      for (int i = 0; i < 4; ++i)
        #pragma unroll
        for (int j = 0; j < 4; ++j) acc[i][j] += av[i]*bv[j];
    }
    __syncthreads();
  }
  #pragma unroll
  for (int i = 0; i < 4; ++i){
    int row = m0 + ty*4 + i;
    #pragma unroll
    for (int j = 0; j < 4; ++j){
      int col = n0 + tx*4 + j;
      dst[(size_t)row*384 + col] = acc[i][j] + bias[col];
    }
  }
}

extern "C" void kernel_launch(void* const* d_in, const int* in_sizes, int n_in,
                              void* d_out, int out_size, void* d_ws, size_t ws_size,
                              hipStream_t stream){
  const float* a      = (const float*)d_in[0];
  const float* z      = (const float*)d_in[1];
  const float* mask   = (const float*)d_in[2];
  const float* ln_a_w = (const float*)d_in[3];
  const float* ln_a_b = (const float*)d_in[4];
  const float* ln_z_w = (const float*)d_in[5];
  const float* ln_z_b = (const float*)d_in[6];
  const float* w_z    = (const float*)d_in[7];
  const float* wq     = (const float*)d_in[8];
  const float* wk     = (const float*)d_in[9];
  const float* wv     = (const float*)d_in[10];
  const float* wg     = (const float*)d_in[11];
  const float* bg     = (const float*)d_in[12];
  const float* wo     = (const float*)d_in[13];
  const float* bo     = (const float*)d_in[14];

  char* ws = (char*)d_ws;
  unsigned short* a_lnB = (unsigned short*)(ws + ((size_t)0u));
  unsigned short* wBt   = (unsigned short*)(ws + ((size_t)1u << 20));
  float* qT   = (float*)(ws + ((size_t)4u << 20));
  float* kT   = (float*)(ws + ((size_t)6u << 20));
  float* vT   = (float*)(ws + ((size_t)8u << 20));
  float* g    = (float*)(ws + ((size_t)10u << 20));
  float* og   = (float*)(ws + ((size_t)12u << 20));
  unsigned short* wwB = (unsigned short*)(ws + ((size_t)14u << 20));
  float* TU   = (float*)(ws + ((size_t)14u << 20) + 8192);
  float* part = (float*)(ws + ((size_t)15u << 20));
  unsigned short* pb  = (unsigned short*)(ws + ((size_t)24u << 20));

  hipLaunchKernelGGL(prep_kernel, dim3(2561), dim3(256), 0, stream, a, ln_a_w, ln_a_b,
                     ln_z_w, ln_z_b, w_z, wq, wk, wv, wg, a_lnB, wBt, wwB, TU);
  hipLaunchKernelGGL(qkvg_kernel, dim3(24,16), dim3(256), 0, stream, a_lnB, wBt, bg, qT, kT, vT, g);
  hipLaunchKernelGGL(zbias_kernel, dim3(4096), dim3(256), 0, stream, z, wwB, TU, pb);
  hipLaunchKernelGGL(attn_kernel, dim3(4,16,16), dim3(256), 0, stream, qT, kT, vT, pb, mask, part);
  hipLaunchKernelGGL(merge_kernel, dim3(64), dim3(256), 0, stream, part, g, og);
  hipLaunchKernelGGL(gemm384, dim3(6,16), dim3(256), 0, stream, og, wo, bo, (float*)d_out);
}

// Round 4
// 271.752 us; speedup vs baseline: 1.6875x; 1.1113x over previous
//
#include <hip/hip_runtime.h>
#include <hip/hip_bf16.h>

typedef float f32x4 __attribute__((ext_vector_type(4)));
typedef short s16x8 __attribute__((ext_vector_type(8)));
typedef short s16x4 __attribute__((ext_vector_type(4)));

__device__ __forceinline__ unsigned short f2bf(float x){
  unsigned u = __float_as_uint(x);
  u += 0x7fffu + ((u >> 16) & 1u);
  return (unsigned short)(u >> 16);
}
__device__ __forceinline__ float bf2f(unsigned short h){
  return __uint_as_float(((unsigned)h) << 16);
}
__device__ __forceinline__ unsigned pk_bf(float a, float b){
  __hip_bfloat162 t = __float22bfloat162_rn(make_float2(a, b));
  return *reinterpret_cast<unsigned*>(&t);
}

// ---------------- fused prep: wprep (blocks 0..2303), ln_a (2304..2559), setup (2560) ----------------
__global__ __launch_bounds__(256) void prep_kernel(const float* __restrict__ a, const float* __restrict__ ln_a_w,
                             const float* __restrict__ ln_a_b, const float* __restrict__ lnzw,
                             const float* __restrict__ lnzb, const float* __restrict__ w_z,
                             const float* __restrict__ wq, const float* __restrict__ wk,
                             const float* __restrict__ wv, const float* __restrict__ wg,
                             unsigned short* __restrict__ a_lnB, unsigned short* __restrict__ wBt,
                             unsigned short* __restrict__ wwB, float* __restrict__ TU){
  int bid = blockIdx.x, tid = threadIdx.x;
  if (bid < 2304){
    int idx = bid*256 + tid;                  // 1536*384 = 589824
    int col = idx / 384, k = idx - col*384;
    int which = (col >> 7) / 3;               // 0..3
    int c = col - which*384;
    const float* src = which == 0 ? wq : which == 1 ? wk : which == 2 ? wv : wg;
    float v = src[(size_t)k*384 + c];
    if (which == 0) v *= 0.20412414523193154f;
    wBt[idx] = f2bf(v);
  } else if (bid < 2560){
    int r = (bid - 2304)*4 + (tid >> 6), l = tid & 63;
    const float* ap = a + (size_t)r*384;
    float x[6]; float s = 0.f, sq = 0.f;
    #pragma unroll
    for (int i = 0; i < 6; ++i){ x[i] = ap[i*64 + l]; s += x[i]; sq += x[i]*x[i]; }
    #pragma unroll
    for (int off = 32; off; off >>= 1){ s += __shfl_xor(s, off); sq += __shfl_xor(sq, off); }
    float mu = s*(1.f/384.f);
    float var = sq*(1.f/384.f) - mu*mu;
    float rs = rsqrtf(var + 1e-5f);
    #pragma unroll
    for (int i = 0; i < 6; ++i){ int c = i*64 + l; a_lnB[(size_t)r*384 + c] = f2bf((x[i]-mu)*rs*ln_a_w[c] + ln_a_b[c]); }
  } else {
    if (tid < 128){
      float lw = lnzw[tid];
      #pragma unroll
      for (int h = 0; h < 16; ++h) wwB[tid*16 + h] = f2bf(lw * w_z[tid*16 + h]);
    }
    if (tid < 16){
      float T = 0.f, U = 0.f;
      for (int c = 0; c < 128; ++c){ T += lnzw[c]*w_z[c*16 + tid]; U += lnzb[c]*w_z[c*16 + tid]; }
      TU[tid] = T; TU[16 + tid] = U;
    }
  }
}

// ---------------- fused QKVG: [1024x384]bf16 @ [384x1536]bf16 via MFMA ----------------
__global__ __launch_bounds__(256) void qkvg_kernel(const unsigned short* __restrict__ AB,
                                                   const unsigned short* __restrict__ wBt,
                                                   const float* __restrict__ bg,
                                                   float* __restrict__ qT, float* __restrict__ kT,
                                                   float* __restrict__ vT, float* __restrict__ g){
  __shared__ short Al[64*8*8];   // [64 rows][8 units of 8 bf16], unit XOR-swizzled by row&7
  __shared__ short Bl[64*8*8];
  int tid = threadIdx.x;
  int wave = tid >> 6, lane = tid & 63, l15 = lane & 15, sub = lane >> 4;
  int n0 = blockIdx.x*64, m0 = blockIdx.y*64;
  f32x4 acc[4];
  #pragma unroll
  for (int c = 0; c < 4; ++c) acc[c] = (f32x4){0.f,0.f,0.f,0.f};
  const s16x8* Ag = (const s16x8*)AB;    // row stride 48 units
  const s16x8* Bg = (const s16x8*)wBt;
  s16x8* Al8 = (s16x8*)Al; s16x8* Bl8 = (s16x8*)Bl;
  for (int ks = 0; ks < 6; ++ks){
    int k0u = ks*8;
    #pragma unroll
    for (int j = 0; j < 2; ++j){
      int idx = tid*2 + j;
      int row = idx >> 3, u = idx & 7;
      Al8[row*8 + (u ^ (row & 7))] = Ag[(size_t)(m0 + row)*48 + k0u + u];
      Bl8[row*8 + (u ^ (row & 7))] = Bg[(size_t)(n0 + row)*48 + k0u + u];
    }
    __syncthreads();
    #pragma unroll
    for (int kk = 0; kk < 2; ++kk){
      int arow = wave*16 + l15;
      s16x8 af = Al8[arow*8 + ((kk*4 + sub) ^ (arow & 7))];
      #pragma unroll
      for (int c = 0; c < 4; ++c){
        int brow = c*16 + l15;
        s16x8 bf = Bl8[brow*8 + ((kk*4 + sub) ^ (brow & 7))];
        acc[c] = __builtin_amdgcn_mfma_f32_16x16x32_bf16(af, bf, acc[c], 0, 0, 0);
      }
    }
    __syncthreads();
  }
  int which = blockIdx.x / 6;            // 0:q 1:k 2:v 3:g
  int cb = n0 - which*384;
  #pragma unroll
  for (int c = 0; c < 4; ++c){
    int col = cb + c*16 + l15;
    #pragma unroll
    for (int r = 0; r < 4; ++r){
      int row = m0 + wave*16 + sub*4 + r;
      float v = acc[c][r];
      if (which == 3){
        float t = v + bg[col];
        g[(size_t)row*384 + col] = 1.f/(1.f + __expf(-t));
      } else {
        int h = col/24, d = col - h*24;
        float* dst = which == 0 ? qT : which == 1 ? kT : vT;
        dst[((size_t)(h << 10) + row)*24 + d] = v;
      }
    }
  }
}

// ---------------- z bias: LN(z) @ w_z via bf16 MFMA; stats via MFMA row-sums (A*ones) ----------------
__global__ __launch_bounds__(256) void zbias_kernel(const float* __restrict__ z, const unsigned short* __restrict__ wwB,
                                                    const float* __restrict__ TU, unsigned short* __restrict__ pb){
  __shared__ short zt[64*16*8];        // 64 pairs x 128 ch bf16, 16B-unit XOR swizzle
  __shared__ short zq[64*16*8];        // same layout, z^2 in bf16
  __shared__ float2 stats[64];         // (mu, rs) per pair
  __shared__ float accT[64][17];       // transposed MFMA result for coalesced pb stores
  int tid = threadIdx.x;
  int wave = tid >> 6, lane = tid & 63;
  int h = lane & 15, sub = lane >> 4;
  s16x8 bfr[4];
  #pragma unroll
  for (int kc = 0; kc < 4; ++kc)
    #pragma unroll
    for (int j = 0; j < 8; ++j) bfr[kc][j] = (short)wwB[(kc*32 + sub*8 + j)*16 + h];
  s16x8 ones1;                         // B with col0 = 1.0 (all k), else 0 -> D[:,0] = row sums
  #pragma unroll
  for (int j = 0; j < 8; ++j) ones1[j] = (h == 0) ? (short)0x3F80 : (short)0;
  int eh = tid >> 4, epl0 = (tid & 15)*4;   // epilogue mapping: thread -> (h, pl0..pl0+3)
  float Te = TU[eh], Ue = TU[16 + eh];
  for (int it = 0; it < 4; ++it){
    int tile = blockIdx.x + it*4096;   // 16384 tiles of 64 pairs
    size_t pairBase = (size_t)tile*64;
    const f32x4* zin = ((const f32x4*)z) + pairBase*32;
    #pragma unroll
    for (int i = 0; i < 8; ++i){
      int f4i = i*256 + tid;
      f32x4 v = zin[f4i];
      int pair = f4i >> 5, c4 = f4i & 31;
      unsigned lo  = pk_bf(v.x, v.y),         hi  = pk_bf(v.z, v.w);
      unsigned qlo = pk_bf(v.x*v.x, v.y*v.y), qhi = pk_bf(v.z*v.z, v.w*v.w);
      int idx = (pair*16 + ((c4 >> 1) ^ (pair & 7)))*2 + (c4 & 1);
      ((uint2*)zt)[idx] = make_uint2(lo, hi);
      ((uint2*)zq)[idx] = make_uint2(qlo, qhi);
    }
    __syncthreads();
    int row = wave*16 + h;
    f32x4 acc  = {0.f, 0.f, 0.f, 0.f};
    f32x4 accS = {0.f, 0.f, 0.f, 0.f};
    f32x4 accQ = {0.f, 0.f, 0.f, 0.f};
    const s16x8* zt8 = (const s16x8*)zt;
    const s16x8* zq8 = (const s16x8*)zq;
    #pragma unroll
    for (int kc = 0; kc < 4; ++kc){
      int u = (kc*4 + sub) ^ (row & 7);
      s16x8 af = zt8[row*16 + u];
      s16x8 aq = zq8[row*16 + u];
      acc  = __builtin_amdgcn_mfma_f32_16x16x32_bf16(af, bfr[kc], acc, 0, 0, 0);
      accS = __builtin_amdgcn_mfma_f32_16x16x32_bf16(af, ones1, accS, 0, 0, 0);
      accQ = __builtin_amdgcn_mfma_f32_16x16x32_bf16(aq, ones1, accQ, 0, 0, 0);
    }
    #pragma unroll
    for (int r = 0; r < 4; ++r) accT[wave*16 + sub*4 + r][h] = acc[r];
    if (h == 0){
      #pragma unroll
      for (int r = 0; r < 4; ++r){
        float mu = accS[r]*(1.f/128.f);
        float var = accQ[r]*(1.f/128.f) - mu*mu;
        stats[wave*16 + sub*4 + r] = make_float2(mu, rsqrtf(var + 1e-5f));
      }
    }
    __syncthreads();
    ushort4 ov;
    {
      float2 st0 = stats[epl0+0], st1 = stats[epl0+1], st2 = stats[epl0+2], st3 = stats[epl0+3];
      ov.x = f2bf(st0.y*(accT[epl0+0][eh] - st0.x*Te) + Ue);
      ov.y = f2bf(st1.y*(accT[epl0+1][eh] - st1.x*Te) + Ue);
      ov.z = f2bf(st2.y*(accT[epl0+2][eh] - st2.x*Te) + Ue);
      ov.w = f2bf(st3.y*(accT[epl0+3][eh] - st3.x*Te) + Ue);
    }
    *(ushort4*)(pb + ((size_t)eh << 20) + pairBase + epl0) = ov;
    __syncthreads();
  }
}

// ---------------- attention: lane = q row, wave = kk chunk; grouped online softmax ----------------
__global__ __launch_bounds__(256) void attn_kernel(const float* __restrict__ qT, const float* __restrict__ kT,
                                                   const float* __restrict__ vT, const unsigned short* __restrict__ pb,
                                                   const float* __restrict__ mask, float* __restrict__ part){
  __shared__ float mlds[4][64][29];
  int s = blockIdx.x, qb = blockIdx.y, h = blockIdx.z;
  int wave = threadIdx.x >> 6, lane = threadIdx.x & 63;
  int q = qb*64 + lane;
  const float4* qp = (const float4*)(qT + ((size_t)(h << 10) + q)*24);
  float qv[24];
  #pragma unroll
  for (int i = 0; i < 6; ++i){ float4 t = qp[i]; qv[4*i] = t.x; qv[4*i+1] = t.y; qv[4*i+2] = t.z; qv[4*i+3] = t.w; }
  const unsigned short* pbrow = pb + ((size_t)h << 20) + (size_t)q*1024;
  float m = -1e30f, lsum = 0.f, ov[24];
  #pragma unroll
  for (int i = 0; i < 24; ++i) ov[i] = 0.f;
  int kk0 = s*256 + wave*64;
  for (int grp = 0; grp < 16; ++grp){
    int kkb = kk0 + grp*4;
    s16x4 pbv = *(const s16x4*)(pbrow + kkb);
    float4 mk = *(const float4*)(mask + kkb);
    float lg[4];
    #pragma unroll
    for (int j = 0; j < 4; ++j){
      const float4* kp = (const float4*)(kT + ((size_t)(h << 10) + kkb + j)*24);
      float d0 = 0.f, d1 = 0.f, d2 = 0.f, d3 = 0.f;
      #pragma unroll
      for (int i = 0; i < 6; ++i){
        float4 kf = kp[i];
        d0 += qv[4*i]*kf.x; d1 += qv[4*i+1]*kf.y; d2 += qv[4*i+2]*kf.z; d3 += qv[4*i+3]*kf.w;
      }
      float mb = j == 0 ? mk.x : j == 1 ? mk.y : j == 2 ? mk.z : mk.w;
      lg[j] = (d0 + d1) + (d2 + d3) + bf2f((unsigned short)pbv[j]) + 1e9f*(mb - 1.f);
    }
    float gm = fmaxf(fmaxf(lg[0], lg[1]), fmaxf(lg[2], lg[3]));
    if (gm > m){
      float corr = __expf(m - gm);
      lsum *= corr;
      #pragma unroll
      for (int i = 0; i < 24; ++i) ov[i] *= corr;
      m = gm;
    }
    #pragma unroll
    for (int j = 0; j < 4; ++j){
      float p = __expf(lg[j] - m);
      lsum += p;
      const float4* vp = (const float4*)(vT + ((size_t)(h << 10) + kkb + j)*24);
      #pragma unroll
      for (int i = 0; i < 6; ++i){
        float4 vf = vp[i];
        ov[4*i]   += p*vf.x;
        ov[4*i+1] += p*vf.y;
        ov[4*i+2] += p*vf.z;
        ov[4*i+3] += p*vf.w;
      }
    }
  }
  mlds[wave][lane][0] = m; mlds[wave][lane][1] = lsum;
  #pragma unroll
  for (int i = 0; i < 24; ++i) mlds[wave][lane][2+i] = ov[i];
  __syncthreads();
  if (wave == 0){
    float M = -1e30f, L = 0.f, O[24];
    #pragma unroll
    for (int i = 0; i < 24; ++i) O[i] = 0.f;
    #pragma unroll
    for (int w = 0; w < 4; ++w){
      float mi = mlds[w][lane][0], li = mlds[w][lane][1];
      float nm = fmaxf(M, mi);
      float c1 = __expf(M - nm), c2 = __expf(mi - nm);
      L = L*c1 + li*c2;
      #pragma unroll
      for (int i = 0; i < 24; ++i) O[i] = O[i]*c1 + mlds[w][lane][2+i]*c2;
      M = nm;
    }
    float* pw = part + ((size_t)((h*16 + qb)*4 + s)*64 + lane)*32;
    *(float2*)pw = make_float2(M, L);
    #pragma unroll
    for (int i = 0; i < 6; ++i) *(float4*)(pw + 4 + i*4) = *(float4*)&O[i*4];
  }
}

// ---------------- merge 4 split-partials, apply gate (vectorized, 256x64) ----------------
__global__ __launch_bounds__(64) void merge_kernel(const float* __restrict__ part, const float* __restrict__ g,
                                                   float* __restrict__ og){
  int gid = blockIdx.x*64 + threadIdx.x;
  int h = gid >> 10, q = gid & 1023;
  float M = -1e30f, L = 0.f, O[24];
  #pragma unroll
  for (int i = 0; i < 24; ++i) O[i] = 0.f;
  #pragma unroll
  for (int sp = 0; sp < 4; ++sp){
    const float* pr = part + ((size_t)((h*16 + (q >> 6))*4 + sp)*64 + (q & 63))*32;
    float2 ml = *(const float2*)pr;
    float nm = fmaxf(M, ml.x);
    float c1 = __expf(M - nm), c2 = __expf(ml.y != ml.y ? 0.f : ml.x - nm); // keep simple: recompute below
    c2 = __expf(ml.x - nm);
    L = L*c1 + ml.y*c2;
    #pragma unroll
    for (int i = 0; i < 6; ++i){
      float4 pv = *(const float4*)(pr + 4 + i*4);
      O[4*i]   = O[4*i]  *c1 + pv.x*c2;
      O[4*i+1] = O[4*i+1]*c1 + pv.y*c2;
      O[4*i+2] = O[4*i+2]*c1 + pv.z*c2;
      O[4*i+3] = O[4*i+3]*c1 + pv.w*c2;
    }
    M = nm;
  }
  float inv = 1.f/L;
  size_t base = (size_t)q*384 + h*24;
  #pragma unroll
  for (int i = 0; i < 6; ++i){
    float4 gv = *(const float4*)(g + base + i*4);
    float4 o4;
    o4.x = gv.x*O[4*i]*inv; o4.y = gv.y*O[4*i+1]*inv;
    o4.z = gv.z*O[4*i+2]*inv; o4.w = gv.w*O[4*i+3]*inv;
    *(float4*)(og + base + i*4) = o4;
  }
}

// ---------------- f32 GEMM for final projection: og[1024x384] @ wo[384x384] + bo ----------------
__global__ __launch_bounds__(256) void gemm384(const float* __restrict__ A, const float* __restrict__ B,
                                               const float* __restrict__ bias, float* __restrict__ dst){
  __shared__ float As[16][68];
  __shared__ float Bs[16][64];
  int tid = threadIdx.x;
  int tx = tid & 15, ty = tid >> 4;
  int n0 = blockIdx.x*64, m0 = blockIdx.y*64;
  float acc[4][4];
  #pragma unroll
  for (int i = 0; i < 4; ++i)
    #pragma unroll
    for (int j = 0; j < 4; ++j) acc[i][j] = 0.f;
  for (int kc = 0; kc < 24; ++kc){
    {
      int m = tid >> 2, k4 = tid & 3;
      float4 v = *(const float4*)(A + (size_t)(m0 + m)*384 + kc*16 + k4*4);
      As[k4*4+0][m] = v.x; As[k4*4+1][m] = v.y; As[k4*4+2][m] = v.z; As[k4*4+3][m] = v.w;
    }
    {
      int kB = tid >> 4, n4 = tid & 15;
      float4 v = *(const float4*)(B + (size_t)(kc*16 + kB)*384 + n0 + n4*4);
      *(float4*)&Bs[kB][n4*4] = v;
    }
    __syncthreads();
    #pragma unroll
    for (int k = 0; k < 16; ++k){
      float4 a4 = *(const float4*)&As[k][ty*4];
      float4 b4 = *(const float4*)&Bs[k][tx*4];
      float av[4] = {a4.x, a4.y, a4.z, a4.w};
      float bv[4] = {b4.x, b4.y, b4.z, b4.w};
      #pragma unroll
      for (int i = 0; i < 4; ++i)
        #pragma unroll
        for (int j = 0; j < 4; ++j) acc[i][j] += av[i]*bv[j];
    }
    __syncthreads();
  }
  #pragma unroll
  for (int i = 0; i < 4; ++i){
    int row = m0 + ty*4 + i;
    #pragma unroll
    for (int j = 0; j < 4; ++j){
      int col = n0 + tx*4 + j;
      dst[(size_t)row*384 + col] = acc[i][j] + bias[col];
    }
  }
}

extern "C" void kernel_launch(void* const* d_in, const int* in_sizes, int n_in,
                              void* d_out, int out_size, void* d_ws, size_t ws_size,
                              hipStream_t stream){
  const float* a      = (const float*)d_in[0];
  const float* z      = (const float*)d_in[1];
  const float* mask   = (const float*)d_in[2];
  const float* ln_a_w = (const float*)d_in[3];
  const float* ln_a_b = (const float*)d_in[4];
  const float* ln_z_w = (const float*)d_in[5];
  const float* ln_z_b = (const float*)d_in[6];
  const float* w_z    = (const float*)d_in[7];
  const float* wq     = (const float*)d_in[8];
  const float* wk     = (const float*)d_in[9];
  const float* wv     = (const float*)d_in[10];
  const float* wg     = (const float*)d_in[11];
  const float* bg     = (const float*)d_in[12];
  const float* wo     = (const float*)d_in[13];
  const float* bo     = (const float*)d_in[14];

  char* ws = (char*)d_ws;
  unsigned short* a_lnB = (unsigned short*)(ws + ((size_t)0u));
  unsigned short* wBt   = (unsigned short*)(ws + ((size_t)1u << 20));
  float* qT   = (float*)(ws + ((size_t)4u << 20));
  float* kT   = (float*)(ws + ((size_t)6u << 20));
  float* vT   = (float*)(ws + ((size_t)8u << 20));
  float* g    = (float*)(ws + ((size_t)10u << 20));
  float* og   = (float*)(ws + ((size_t)12u << 20));
  unsigned short* wwB = (unsigned short*)(ws + ((size_t)14u << 20));
  float* TU   = (float*)(ws + ((size_t)14u << 20) + 8192);
  float* part = (float*)(ws + ((size_t)15u << 20));
  unsigned short* pb  = (unsigned short*)(ws + ((size_t)24u << 20));

  hipLaunchKernelGGL(prep_kernel, dim3(2561), dim3(256), 0, stream, a, ln_a_w, ln_a_b,
                     ln_z_w, ln_z_b, w_z, wq, wk, wv, wg, a_lnB, wBt, wwB, TU);
  hipLaunchKernelGGL(qkvg_kernel, dim3(24,16), dim3(256), 0, stream, a_lnB, wBt, bg, qT, kT, vT, g);
  hipLaunchKernelGGL(zbias_kernel, dim3(4096), dim3(256), 0, stream, z, wwB, TU, pb);
  hipLaunchKernelGGL(attn_kernel, dim3(4,16,16), dim3(256), 0, stream, qT, kT, vT, pb, mask, part);
  hipLaunchKernelGGL(merge_kernel, dim3(256), dim3(64), 0, stream, part, g, og);
  hipLaunchKernelGGL(gemm384, dim3(6,16), dim3(256), 0, stream, og, wo, bo, (float*)d_out);
}